// Round 8
// baseline (1314.183 us; speedup 1.0000x reference)
//
#include <hip/hip_runtime.h>
#include <math.h>

#define F_IN 128
#define HID  32

#define NPB   256      // nodes per bucket (dst >> 8)
#define MAXNB 1024     // max buckets supported by the one-block scan
#define EPB   8192     // edges per block in coarse passes (293 blocks @ 2.4M)
#define BLK_E 1024     // threads per block for coarse passes
#define BLK_C 512      // threads per block for k_bcsr

__device__ __forceinline__ void fma4(float4& a, float s, const float4& w) {
    a.x = fmaf(s, w.x, a.x);
    a.y = fmaf(s, w.y, a.y);
    a.z = fmaf(s, w.z, a.z);
    a.w = fmaf(s, w.w, a.w);
}

// ================= binned CSR build =================

__global__ __launch_bounds__(BLK_E) void k_bhist(const int* __restrict__ dst,
                                                 int* __restrict__ bin_hist,
                                                 int e, int nbuckets) {
    __shared__ int h[MAXNB];
    int tid = threadIdx.x;
    for (int i = tid; i < nbuckets; i += BLK_E) h[i] = 0;
    __syncthreads();
    int base = blockIdx.x * EPB;
    int end = base + EPB; if (end > e) end = e;
    for (int i = base + tid; i < end; i += BLK_E)
        atomicAdd(&h[dst[i] >> 8], 1);
    __syncthreads();
    for (int i = tid; i < nbuckets; i += BLK_E)
        if (h[i]) atomicAdd(&bin_hist[i], h[i]);
}

__global__ __launch_bounds__(1024) void k_bscan(const int* __restrict__ bin_hist,
                                                int* __restrict__ bin_off,
                                                int* __restrict__ bin_cur,
                                                int* __restrict__ offsets,
                                                int nbuckets, int n, int e) {
    __shared__ int sh[MAXNB];
    int t = threadIdx.x;
    int v = (t < nbuckets) ? bin_hist[t] : 0;
    sh[t] = v; __syncthreads();
    for (int off = 1; off < MAXNB; off <<= 1) {
        int a = (t >= off) ? sh[t - off] : 0;
        __syncthreads();
        sh[t] += a;
        __syncthreads();
    }
    int excl = sh[t] - v;
    if (t < nbuckets) { bin_off[t] = excl; bin_cur[t] = excl; }
    if (t == 0) { bin_off[nbuckets] = e; offsets[n] = e; }
}

__global__ __launch_bounds__(BLK_E) void k_bpart(const int* __restrict__ src,
                                                 const int* __restrict__ dst,
                                                 int* __restrict__ bin_cur,
                                                 unsigned* __restrict__ tmp,
                                                 int e, int nbuckets) {
    __shared__ int h[MAXNB];
    __shared__ int lc[MAXNB];
    int tid = threadIdx.x;
    for (int i = tid; i < nbuckets; i += BLK_E) h[i] = 0;
    __syncthreads();
    int base = blockIdx.x * EPB;
    int end = base + EPB; if (end > e) end = e;
    for (int i = base + tid; i < end; i += BLK_E)
        atomicAdd(&h[dst[i] >> 8], 1);
    __syncthreads();
    for (int i = tid; i < nbuckets; i += BLK_E) {
        int c = h[i];
        h[i] = c ? atomicAdd(&bin_cur[i], c) : 0;
        lc[i] = 0;
    }
    __syncthreads();
    for (int i = base + tid; i < end; i += BLK_E) {
        int d = dst[i];
        int b = d >> 8;
        int r = atomicAdd(&lc[b], 1);
        tmp[h[b] + r] = (unsigned)src[i] | ((unsigned)(d & (NPB - 1)) << 18);
    }
}

// 512 threads: edge loops stride 512; counting/scan confined to t<256.
__global__ __launch_bounds__(BLK_C) void k_bcsr(const unsigned* __restrict__ tmp,
                                                const int* __restrict__ bin_off,
                                                int* __restrict__ es,
                                                int* __restrict__ offsets,
                                                float* __restrict__ dis, int n) {
    __shared__ int cnt[NPB];
    __shared__ int sh[NPB];
    __shared__ int cur[NPB];
    int b = blockIdx.x, t = threadIdx.x;
    if (t < NPB) cnt[t] = 0;
    __syncthreads();
    int s0 = bin_off[b], s1 = bin_off[b + 1];
    for (int i = s0 + t; i < s1; i += BLK_C)
        atomicAdd(&cnt[(tmp[i] >> 18) & (NPB - 1)], 1);
    __syncthreads();
    int v = (t < NPB) ? cnt[t] : 0;
    if (t < NPB) sh[t] = v;
    __syncthreads();
    for (int off = 1; off < NPB; off <<= 1) {
        int a = (t < NPB && t >= off) ? sh[t - off] : 0;
        __syncthreads();
        if (t < NPB) sh[t] += a;
        __syncthreads();
    }
    if (t < NPB) {
        int excl = sh[t] - v;
        int node = b * NPB + t;
        if (node < n) {
            offsets[node] = s0 + excl;
            dis[node] = rsqrtf((float)(v + 1));
        }
        cur[t] = excl;
    }
    __syncthreads();
    for (int i = s0 + t; i < s1; i += BLK_C) {
        unsigned w = tmp[i];
        int dl = (w >> 18) & (NPB - 1);
        int r = atomicAdd(&cur[dl], 1);
        es[s0 + r] = (int)(w & 0x3FFFFu);
    }
}

// ================= transforms =================

// Staging-free, software-pipelined: W in LDS; x loaded with explicit
// next-ks prefetch. __launch_bounds__(256,4) caps VGPR at ~128 so the
// allocator keeps 8 float4 loads in flight.
__global__ __launch_bounds__(256, 4) void k_gemm1(const float* __restrict__ x,
                                                  const float* __restrict__ W,
                                                  const float* __restrict__ dis,
                                                  float* __restrict__ u, int n) {
    __shared__ float Ws[F_IN * HID];
    int tid = threadIdx.x;
    for (int i = tid; i < F_IN * HID; i += 256) Ws[i] = W[i];
    int node0 = blockIdx.x * 128;
    int cg = tid & 7, gq = tid >> 3;
    int row[4];
#pragma unroll
    for (int m = 0; m < 4; ++m) {
        int node = node0 + gq + 32 * m;
        row[m] = (node < n) ? node : 0;
    }
    const float4* x4 = (const float4*)x;
    float4 acc[4];
#pragma unroll
    for (int m = 0; m < 4; ++m) acc[m] = make_float4(0.f, 0.f, 0.f, 0.f);
    float4 xv[4], xn[4];
#pragma unroll
    for (int m = 0; m < 4; ++m) xv[m] = x4[(size_t)row[m] * 32 + 0];
    __syncthreads();
#pragma unroll
    for (int ks = 0; ks < 32; ++ks) {
        if (ks < 31) {
#pragma unroll
            for (int m = 0; m < 4; ++m) xn[m] = x4[(size_t)row[m] * 32 + ks + 1];
        }
        float4 w0 = *(const float4*)&Ws[(ks * 4 + 0) * HID + cg * 4];
        float4 w1 = *(const float4*)&Ws[(ks * 4 + 1) * HID + cg * 4];
        float4 w2 = *(const float4*)&Ws[(ks * 4 + 2) * HID + cg * 4];
        float4 w3 = *(const float4*)&Ws[(ks * 4 + 3) * HID + cg * 4];
#pragma unroll
        for (int m = 0; m < 4; ++m) {
            fma4(acc[m], xv[m].x, w0);
            fma4(acc[m], xv[m].y, w1);
            fma4(acc[m], xv[m].z, w2);
            fma4(acc[m], xv[m].w, w3);
        }
#pragma unroll
        for (int m = 0; m < 4; ++m) xv[m] = xn[m];
    }
#pragma unroll
    for (int m = 0; m < 4; ++m) {
        int node = node0 + gq + 32 * m;
        if (node < n) {
            float ds = dis[node];
            float4 r;
            r.x = acc[m].x * ds; r.y = acc[m].y * ds;
            r.z = acc[m].z * ds; r.w = acc[m].w * ds;
            *(float4*)&u[(size_t)node * HID + cg * 4] = r;
        }
    }
}

__global__ __launch_bounds__(256, 4) void k_gemm2(const float* __restrict__ h,
                                                  const float* __restrict__ W,
                                                  const float* __restrict__ dis,
                                                  float* __restrict__ u, int n) {
    __shared__ float Ws[HID * HID];
    int tid = threadIdx.x;
    for (int i = tid; i < HID * HID; i += 256) Ws[i] = W[i];
    int node0 = blockIdx.x * 128;
    int cg = tid & 7, gq = tid >> 3;
    int row[4];
#pragma unroll
    for (int m = 0; m < 4; ++m) {
        int node = node0 + gq + 32 * m;
        row[m] = (node < n) ? node : 0;
    }
    const float4* h4 = (const float4*)h;
    float4 acc[4];
#pragma unroll
    for (int m = 0; m < 4; ++m) acc[m] = make_float4(0.f, 0.f, 0.f, 0.f);
    float4 xv[4], xn[4];
#pragma unroll
    for (int m = 0; m < 4; ++m) xv[m] = h4[(size_t)row[m] * 8 + 0];
    __syncthreads();
#pragma unroll
    for (int ks = 0; ks < 8; ++ks) {
        if (ks < 7) {
#pragma unroll
            for (int m = 0; m < 4; ++m) xn[m] = h4[(size_t)row[m] * 8 + ks + 1];
        }
        float4 w0 = *(const float4*)&Ws[(ks * 4 + 0) * HID + cg * 4];
        float4 w1 = *(const float4*)&Ws[(ks * 4 + 1) * HID + cg * 4];
        float4 w2 = *(const float4*)&Ws[(ks * 4 + 2) * HID + cg * 4];
        float4 w3 = *(const float4*)&Ws[(ks * 4 + 3) * HID + cg * 4];
#pragma unroll
        for (int m = 0; m < 4; ++m) {
            fma4(acc[m], xv[m].x, w0);
            fma4(acc[m], xv[m].y, w1);
            fma4(acc[m], xv[m].z, w2);
            fma4(acc[m], xv[m].w, w3);
        }
#pragma unroll
        for (int m = 0; m < 4; ++m) xv[m] = xn[m];
    }
#pragma unroll
    for (int m = 0; m < 4; ++m) {
        int node = node0 + gq + 32 * m;
        if (node < n) {
            float ds = dis[node];
            float4 r;
            r.x = acc[m].x * ds; r.y = acc[m].y * ds;
            r.z = acc[m].z * ds; r.w = acc[m].w * ds;
            *(float4*)&u[(size_t)node * HID + cg * 4] = r;
        }
    }
}

// ================= gather aggregation =================

__global__ __launch_bounds__(256) void k_gather32(const float4* __restrict__ u4,
                                                  const int* __restrict__ es,
                                                  const int* __restrict__ offsets,
                                                  const float* __restrict__ dis,
                                                  const float* __restrict__ b,
                                                  float4* __restrict__ h4, int n) {
    int t = blockIdx.x * 256 + threadIdx.x;
    int node = t >> 3, q = t & 7;
    if (node >= n) return;
    int s0 = offsets[node];
    int s1 = offsets[node + 1];
    float4 acc = u4[(size_t)node * 8 + q];   // self-loop
    int ei = s0;
    for (; ei + 4 <= s1; ei += 4) {
        int e0 = es[ei], e1 = es[ei + 1], e2 = es[ei + 2], e3 = es[ei + 3];
        float4 v0 = u4[(size_t)e0 * 8 + q];
        float4 v1 = u4[(size_t)e1 * 8 + q];
        float4 v2 = u4[(size_t)e2 * 8 + q];
        float4 v3 = u4[(size_t)e3 * 8 + q];
        acc.x += (v0.x + v1.x) + (v2.x + v3.x);
        acc.y += (v0.y + v1.y) + (v2.y + v3.y);
        acc.z += (v0.z + v1.z) + (v2.z + v3.z);
        acc.w += (v0.w + v1.w) + (v2.w + v3.w);
    }
    for (; ei < s1; ++ei) {
        int s = es[ei];
        float4 v = u4[(size_t)s * 8 + q];
        acc.x += v.x; acc.y += v.y; acc.z += v.z; acc.w += v.w;
    }
    float ds = dis[node];
    float4 r;
    r.x = fmaxf(fmaf(ds, acc.x, b[q * 4 + 0]), 0.0f);
    r.y = fmaxf(fmaf(ds, acc.y, b[q * 4 + 1]), 0.0f);
    r.z = fmaxf(fmaf(ds, acc.z, b[q * 4 + 2]), 0.0f);
    r.w = fmaxf(fmaf(ds, acc.w, b[q * 4 + 3]), 0.0f);
    h4[(size_t)node * 8 + q] = r;
}

__global__ __launch_bounds__(256) void k_gather32_dot(const float4* __restrict__ u4,
                                                      const int* __restrict__ es,
                                                      const int* __restrict__ offsets,
                                                      const float* __restrict__ dis,
                                                      const float* __restrict__ b,
                                                      const float* __restrict__ W3,
                                                      float* __restrict__ s, int n) {
    int t = blockIdx.x * 256 + threadIdx.x;
    int node = t >> 3, q = t & 7;
    if (node >= n) return;
    int s0 = offsets[node];
    int s1 = offsets[node + 1];
    float4 acc = u4[(size_t)node * 8 + q];
    int ei = s0;
    for (; ei + 4 <= s1; ei += 4) {
        int e0 = es[ei], e1 = es[ei + 1], e2 = es[ei + 2], e3 = es[ei + 3];
        float4 v0 = u4[(size_t)e0 * 8 + q];
        float4 v1 = u4[(size_t)e1 * 8 + q];
        float4 v2 = u4[(size_t)e2 * 8 + q];
        float4 v3 = u4[(size_t)e3 * 8 + q];
        acc.x += (v0.x + v1.x) + (v2.x + v3.x);
        acc.y += (v0.y + v1.y) + (v2.y + v3.y);
        acc.z += (v0.z + v1.z) + (v2.z + v3.z);
        acc.w += (v0.w + v1.w) + (v2.w + v3.w);
    }
    for (; ei < s1; ++ei) {
        int sc = es[ei];
        float4 v = u4[(size_t)sc * 8 + q];
        acc.x += v.x; acc.y += v.y; acc.z += v.z; acc.w += v.w;
    }
    float ds = dis[node];
    float4 r;
    r.x = fmaxf(fmaf(ds, acc.x, b[q * 4 + 0]), 0.0f);
    r.y = fmaxf(fmaf(ds, acc.y, b[q * 4 + 1]), 0.0f);
    r.z = fmaxf(fmaf(ds, acc.z, b[q * 4 + 2]), 0.0f);
    r.w = fmaxf(fmaf(ds, acc.w, b[q * 4 + 3]), 0.0f);
    float p = r.x * W3[q * 4 + 0] + r.y * W3[q * 4 + 1]
            + r.z * W3[q * 4 + 2] + r.w * W3[q * 4 + 3];
    p += __shfl_down(p, 4, 8);
    p += __shfl_down(p, 2, 8);
    p += __shfl_down(p, 1, 8);
    if (q == 0) s[node] = p * ds;
}

__global__ void k_gather1(const float* __restrict__ sv, const int* __restrict__ es,
                          const int* __restrict__ offsets, const float* __restrict__ dis,
                          const float* __restrict__ b3, float* __restrict__ out, int n) {
    int d = blockIdx.x * 256 + threadIdx.x;
    if (d >= n) return;
    float acc = sv[d];
    int s0 = offsets[d], s1 = offsets[d + 1];
    int ei = s0;
    for (; ei + 4 <= s1; ei += 4) {
        float v0 = sv[es[ei]], v1 = sv[es[ei + 1]];
        float v2 = sv[es[ei + 2]], v3 = sv[es[ei + 3]];
        acc += (v0 + v1) + (v2 + v3);
    }
    for (; ei < s1; ++ei) acc += sv[es[ei]];
    float z = dis[d] * acc + b3[0];
    out[d] = 1.0f / (1.0f + expf(-z));
}

// ================= launch =================

extern "C" void kernel_launch(void* const* d_in, const int* in_sizes, int n_in,
                              void* d_out, int out_size, void* d_ws, size_t ws_size,
                              hipStream_t stream) {
    const float* x  = (const float*)d_in[0];
    const int*   ei = (const int*)d_in[1];
    const float* W1 = (const float*)d_in[2];
    const float* b1 = (const float*)d_in[3];
    const float* W2 = (const float*)d_in[4];
    const float* b2 = (const float*)d_in[5];
    const float* W3 = (const float*)d_in[6];
    const float* b3 = (const float*)d_in[7];
    float* out = (float*)d_out;

    int n = out_size;             // 150000
    int e = in_sizes[1] / 2;      // 2400000
    const int* src = ei;
    const int* dst = ei + e;

    int nbuckets = (n + NPB - 1) / NPB;   // 586

    float* A        = (float*)d_ws;                 // n*32 f
    float* B        = A + (size_t)n * HID;          // n*32 f (aliases tmp during CSR build)
    float* dis      = B + (size_t)n * HID;          // n f
    float* Cs       = dis + n;                      // n f
    int*   offsets  = (int*)(Cs + n);               // n+1 i
    int*   es       = offsets + (n + 1);            // e i
    int*   bin_hist = es + e;                       // nbuckets i
    int*   bin_off  = bin_hist + nbuckets;          // nbuckets+1 i
    int*   bin_cur  = bin_off + (nbuckets + 1);     // nbuckets i
    unsigned* tmp   = (unsigned*)B;

    dim3 blk(256);
    int gN    = (n + 255) / 256;
    int gN8   = (n * 8 + 255) / 256;
    int g128  = (n + 127) / 128;
    int gEb   = (e + EPB - 1) / EPB;   // 293

    // ---- CSR build ----
    hipMemsetAsync(bin_hist, 0, (size_t)nbuckets * sizeof(int), stream);
    k_bhist<<<gEb, dim3(BLK_E), 0, stream>>>(dst, bin_hist, e, nbuckets);
    k_bscan<<<1, 1024, 0, stream>>>(bin_hist, bin_off, bin_cur, offsets, nbuckets, n, e);
    k_bpart<<<gEb, dim3(BLK_E), 0, stream>>>(src, dst, bin_cur, tmp, e, nbuckets);
    k_bcsr <<<nbuckets, dim3(BLK_C), 0, stream>>>(tmp, bin_off, es, offsets, dis, n);

    // ---- layer 1 ----
    k_gemm1   <<<g128, blk, 0, stream>>>(x, W1, dis, A, n);
    k_gather32<<<gN8,  blk, 0, stream>>>((const float4*)A, es, offsets, dis, b1, (float4*)B, n);

    // ---- layer 2 (+ fused layer-3 transform) ----
    k_gemm2       <<<g128, blk, 0, stream>>>(B, W2, dis, A, n);
    k_gather32_dot<<<gN8,  blk, 0, stream>>>((const float4*)A, es, offsets, dis, b2, W3, Cs, n);

    // ---- layer 3 aggregation ----
    k_gather1<<<gN, blk, 0, stream>>>(Cs, es, offsets, dis, b3, out, n);
}

// Round 9
// 791.538 us; speedup vs baseline: 1.6603x; 1.6603x over previous
//
#include <hip/hip_runtime.h>
#include <math.h>

#define F_IN 128
#define HID  32

#define NPB   256      // nodes per bucket (dst >> 8)
#define MAXNB 1024     // max buckets supported by the one-block scan
#define EPB   8192     // edges per block in coarse passes (293 blocks @ 2.4M)
#define BLK_E 1024     // threads per block for coarse passes
#define BLK_C 512      // threads per block for k_bcsr

__device__ __forceinline__ void fma4(float4& a, float s, const float4& w) {
    a.x = fmaf(s, w.x, a.x);
    a.y = fmaf(s, w.y, a.y);
    a.z = fmaf(s, w.z, a.z);
    a.w = fmaf(s, w.w, a.w);
}

// ================= binned CSR build =================

__global__ __launch_bounds__(BLK_E) void k_bhist(const int* __restrict__ dst,
                                                 int* __restrict__ bin_hist,
                                                 int e, int nbuckets) {
    __shared__ int h[MAXNB];
    int tid = threadIdx.x;
    for (int i = tid; i < nbuckets; i += BLK_E) h[i] = 0;
    __syncthreads();
    int base = blockIdx.x * EPB;
    int end = base + EPB; if (end > e) end = e;
    for (int i = base + tid; i < end; i += BLK_E)
        atomicAdd(&h[dst[i] >> 8], 1);
    __syncthreads();
    for (int i = tid; i < nbuckets; i += BLK_E)
        if (h[i]) atomicAdd(&bin_hist[i], h[i]);
}

__global__ __launch_bounds__(1024) void k_bscan(const int* __restrict__ bin_hist,
                                                int* __restrict__ bin_off,
                                                int* __restrict__ bin_cur,
                                                int* __restrict__ offsets,
                                                int nbuckets, int n, int e) {
    __shared__ int sh[MAXNB];
    int t = threadIdx.x;
    int v = (t < nbuckets) ? bin_hist[t] : 0;
    sh[t] = v; __syncthreads();
    for (int off = 1; off < MAXNB; off <<= 1) {
        int a = (t >= off) ? sh[t - off] : 0;
        __syncthreads();
        sh[t] += a;
        __syncthreads();
    }
    int excl = sh[t] - v;
    if (t < nbuckets) { bin_off[t] = excl; bin_cur[t] = excl; }
    if (t == 0) { bin_off[nbuckets] = e; offsets[n] = e; }
}

__global__ __launch_bounds__(BLK_E) void k_bpart(const int* __restrict__ src,
                                                 const int* __restrict__ dst,
                                                 int* __restrict__ bin_cur,
                                                 unsigned* __restrict__ tmp,
                                                 int e, int nbuckets) {
    __shared__ int h[MAXNB];
    __shared__ int lc[MAXNB];
    int tid = threadIdx.x;
    for (int i = tid; i < nbuckets; i += BLK_E) h[i] = 0;
    __syncthreads();
    int base = blockIdx.x * EPB;
    int end = base + EPB; if (end > e) end = e;
    for (int i = base + tid; i < end; i += BLK_E)
        atomicAdd(&h[dst[i] >> 8], 1);
    __syncthreads();
    for (int i = tid; i < nbuckets; i += BLK_E) {
        int c = h[i];
        h[i] = c ? atomicAdd(&bin_cur[i], c) : 0;
        lc[i] = 0;
    }
    __syncthreads();
    for (int i = base + tid; i < end; i += BLK_E) {
        int d = dst[i];
        int b = d >> 8;
        int r = atomicAdd(&lc[b], 1);
        tmp[h[b] + r] = (unsigned)src[i] | ((unsigned)(d & (NPB - 1)) << 18);
    }
}

__global__ __launch_bounds__(BLK_C) void k_bcsr(const unsigned* __restrict__ tmp,
                                                const int* __restrict__ bin_off,
                                                int* __restrict__ es,
                                                int* __restrict__ offsets,
                                                float* __restrict__ dis, int n) {
    __shared__ int cnt[NPB];
    __shared__ int sh[NPB];
    __shared__ int cur[NPB];
    int b = blockIdx.x, t = threadIdx.x;
    if (t < NPB) cnt[t] = 0;
    __syncthreads();
    int s0 = bin_off[b], s1 = bin_off[b + 1];
    for (int i = s0 + t; i < s1; i += BLK_C)
        atomicAdd(&cnt[(tmp[i] >> 18) & (NPB - 1)], 1);
    __syncthreads();
    int v = (t < NPB) ? cnt[t] : 0;
    if (t < NPB) sh[t] = v;
    __syncthreads();
    for (int off = 1; off < NPB; off <<= 1) {
        int a = (t < NPB && t >= off) ? sh[t - off] : 0;
        __syncthreads();
        if (t < NPB) sh[t] += a;
        __syncthreads();
    }
    if (t < NPB) {
        int excl = sh[t] - v;
        int node = b * NPB + t;
        if (node < n) {
            offsets[node] = s0 + excl;
            dis[node] = rsqrtf((float)(v + 1));
        }
        cur[t] = excl;
    }
    __syncthreads();
    for (int i = s0 + t; i < s1; i += BLK_C) {
        unsigned w = tmp[i];
        int dl = (w >> 18) & (NPB - 1);
        int r = atomicAdd(&cur[dl], 1);
        es[s0 + r] = (int)(w & 0x3FFFFu);
    }
}

// ================= transforms =================

// Staging-free: W in LDS; x read from global. ks unrolled by PAIRS with
// straight-line named temporaries (a*, b*) -> 8 loads in flight, no private
// arrays carried across iterations (scratch-spill-proof).
__global__ __launch_bounds__(256) void k_gemm1(const float* __restrict__ x,
                                               const float* __restrict__ W,
                                               const float* __restrict__ dis,
                                               float* __restrict__ u, int n) {
    __shared__ float Ws[F_IN * HID];
    int tid = threadIdx.x;
    for (int i = tid; i < F_IN * HID; i += 256) Ws[i] = W[i];
    int node0 = blockIdx.x * 128;
    int cg = tid & 7, gq = tid >> 3;
    int node_a = node0 + gq;
    int r0 = (node_a      < n) ? node_a       : 0;
    int r1 = (node_a + 32 < n) ? node_a + 32  : 0;
    int r2 = (node_a + 64 < n) ? node_a + 64  : 0;
    int r3 = (node_a + 96 < n) ? node_a + 96  : 0;
    const float4* x4 = (const float4*)x;
    const float4* p0 = x4 + (size_t)r0 * 32;
    const float4* p1 = x4 + (size_t)r1 * 32;
    const float4* p2 = x4 + (size_t)r2 * 32;
    const float4* p3 = x4 + (size_t)r3 * 32;
    float4 acc0 = make_float4(0.f, 0.f, 0.f, 0.f);
    float4 acc1 = make_float4(0.f, 0.f, 0.f, 0.f);
    float4 acc2 = make_float4(0.f, 0.f, 0.f, 0.f);
    float4 acc3 = make_float4(0.f, 0.f, 0.f, 0.f);
    __syncthreads();
#pragma unroll
    for (int ks = 0; ks < 32; ks += 2) {
        // 8 independent loads issued back-to-back
        float4 a0 = p0[ks],     a1 = p1[ks],     a2 = p2[ks],     a3 = p3[ks];
        float4 b0 = p0[ks + 1], b1 = p1[ks + 1], b2 = p2[ks + 1], b3 = p3[ks + 1];
        const float* wa = &Ws[(ks * 4) * HID + cg * 4];
        float4 wa0 = *(const float4*)(wa);
        float4 wa1 = *(const float4*)(wa + HID);
        float4 wa2 = *(const float4*)(wa + 2 * HID);
        float4 wa3 = *(const float4*)(wa + 3 * HID);
        fma4(acc0, a0.x, wa0); fma4(acc0, a0.y, wa1); fma4(acc0, a0.z, wa2); fma4(acc0, a0.w, wa3);
        fma4(acc1, a1.x, wa0); fma4(acc1, a1.y, wa1); fma4(acc1, a1.z, wa2); fma4(acc1, a1.w, wa3);
        fma4(acc2, a2.x, wa0); fma4(acc2, a2.y, wa1); fma4(acc2, a2.z, wa2); fma4(acc2, a2.w, wa3);
        fma4(acc3, a3.x, wa0); fma4(acc3, a3.y, wa1); fma4(acc3, a3.z, wa2); fma4(acc3, a3.w, wa3);
        const float* wb = &Ws[((ks + 1) * 4) * HID + cg * 4];
        float4 wb0 = *(const float4*)(wb);
        float4 wb1 = *(const float4*)(wb + HID);
        float4 wb2 = *(const float4*)(wb + 2 * HID);
        float4 wb3 = *(const float4*)(wb + 3 * HID);
        fma4(acc0, b0.x, wb0); fma4(acc0, b0.y, wb1); fma4(acc0, b0.z, wb2); fma4(acc0, b0.w, wb3);
        fma4(acc1, b1.x, wb0); fma4(acc1, b1.y, wb1); fma4(acc1, b1.z, wb2); fma4(acc1, b1.w, wb3);
        fma4(acc2, b2.x, wb0); fma4(acc2, b2.y, wb1); fma4(acc2, b2.z, wb2); fma4(acc2, b2.w, wb3);
        fma4(acc3, b3.x, wb0); fma4(acc3, b3.y, wb1); fma4(acc3, b3.z, wb2); fma4(acc3, b3.w, wb3);
    }
    float4* u4 = (float4*)u;
    if (node_a < n) {
        float ds = dis[node_a];
        float4 r = make_float4(acc0.x * ds, acc0.y * ds, acc0.z * ds, acc0.w * ds);
        u4[(size_t)node_a * 8 + cg] = r;
    }
    if (node_a + 32 < n) {
        float ds = dis[node_a + 32];
        float4 r = make_float4(acc1.x * ds, acc1.y * ds, acc1.z * ds, acc1.w * ds);
        u4[(size_t)(node_a + 32) * 8 + cg] = r;
    }
    if (node_a + 64 < n) {
        float ds = dis[node_a + 64];
        float4 r = make_float4(acc2.x * ds, acc2.y * ds, acc2.z * ds, acc2.w * ds);
        u4[(size_t)(node_a + 64) * 8 + cg] = r;
    }
    if (node_a + 96 < n) {
        float ds = dis[node_a + 96];
        float4 r = make_float4(acc3.x * ds, acc3.y * ds, acc3.z * ds, acc3.w * ds);
        u4[(size_t)(node_a + 96) * 8 + cg] = r;
    }
}

// K=32 variant, same pair-unrolled structure.
__global__ __launch_bounds__(256) void k_gemm2(const float* __restrict__ h,
                                               const float* __restrict__ W,
                                               const float* __restrict__ dis,
                                               float* __restrict__ u, int n) {
    __shared__ float Ws[HID * HID];
    int tid = threadIdx.x;
    for (int i = tid; i < HID * HID; i += 256) Ws[i] = W[i];
    int node0 = blockIdx.x * 128;
    int cg = tid & 7, gq = tid >> 3;
    int node_a = node0 + gq;
    int r0 = (node_a      < n) ? node_a       : 0;
    int r1 = (node_a + 32 < n) ? node_a + 32  : 0;
    int r2 = (node_a + 64 < n) ? node_a + 64  : 0;
    int r3 = (node_a + 96 < n) ? node_a + 96  : 0;
    const float4* h4 = (const float4*)h;
    const float4* p0 = h4 + (size_t)r0 * 8;
    const float4* p1 = h4 + (size_t)r1 * 8;
    const float4* p2 = h4 + (size_t)r2 * 8;
    const float4* p3 = h4 + (size_t)r3 * 8;
    float4 acc0 = make_float4(0.f, 0.f, 0.f, 0.f);
    float4 acc1 = make_float4(0.f, 0.f, 0.f, 0.f);
    float4 acc2 = make_float4(0.f, 0.f, 0.f, 0.f);
    float4 acc3 = make_float4(0.f, 0.f, 0.f, 0.f);
    __syncthreads();
#pragma unroll
    for (int ks = 0; ks < 8; ks += 2) {
        float4 a0 = p0[ks],     a1 = p1[ks],     a2 = p2[ks],     a3 = p3[ks];
        float4 b0 = p0[ks + 1], b1 = p1[ks + 1], b2 = p2[ks + 1], b3 = p3[ks + 1];
        const float* wa = &Ws[(ks * 4) * HID + cg * 4];
        float4 wa0 = *(const float4*)(wa);
        float4 wa1 = *(const float4*)(wa + HID);
        float4 wa2 = *(const float4*)(wa + 2 * HID);
        float4 wa3 = *(const float4*)(wa + 3 * HID);
        fma4(acc0, a0.x, wa0); fma4(acc0, a0.y, wa1); fma4(acc0, a0.z, wa2); fma4(acc0, a0.w, wa3);
        fma4(acc1, a1.x, wa0); fma4(acc1, a1.y, wa1); fma4(acc1, a1.z, wa2); fma4(acc1, a1.w, wa3);
        fma4(acc2, a2.x, wa0); fma4(acc2, a2.y, wa1); fma4(acc2, a2.z, wa2); fma4(acc2, a2.w, wa3);
        fma4(acc3, a3.x, wa0); fma4(acc3, a3.y, wa1); fma4(acc3, a3.z, wa2); fma4(acc3, a3.w, wa3);
        const float* wb = &Ws[((ks + 1) * 4) * HID + cg * 4];
        float4 wb0 = *(const float4*)(wb);
        float4 wb1 = *(const float4*)(wb + HID);
        float4 wb2 = *(const float4*)(wb + 2 * HID);
        float4 wb3 = *(const float4*)(wb + 3 * HID);
        fma4(acc0, b0.x, wb0); fma4(acc0, b0.y, wb1); fma4(acc0, b0.z, wb2); fma4(acc0, b0.w, wb3);
        fma4(acc1, b1.x, wb0); fma4(acc1, b1.y, wb1); fma4(acc1, b1.z, wb2); fma4(acc1, b1.w, wb3);
        fma4(acc2, b2.x, wb0); fma4(acc2, b2.y, wb1); fma4(acc2, b2.z, wb2); fma4(acc2, b2.w, wb3);
        fma4(acc3, b3.x, wb0); fma4(acc3, b3.y, wb1); fma4(acc3, b3.z, wb2); fma4(acc3, b3.w, wb3);
    }
    float4* u4 = (float4*)u;
    if (node_a < n) {
        float ds = dis[node_a];
        float4 r = make_float4(acc0.x * ds, acc0.y * ds, acc0.z * ds, acc0.w * ds);
        u4[(size_t)node_a * 8 + cg] = r;
    }
    if (node_a + 32 < n) {
        float ds = dis[node_a + 32];
        float4 r = make_float4(acc1.x * ds, acc1.y * ds, acc1.z * ds, acc1.w * ds);
        u4[(size_t)(node_a + 32) * 8 + cg] = r;
    }
    if (node_a + 64 < n) {
        float ds = dis[node_a + 64];
        float4 r = make_float4(acc2.x * ds, acc2.y * ds, acc2.z * ds, acc2.w * ds);
        u4[(size_t)(node_a + 64) * 8 + cg] = r;
    }
    if (node_a + 96 < n) {
        float ds = dis[node_a + 96];
        float4 r = make_float4(acc3.x * ds, acc3.y * ds, acc3.z * ds, acc3.w * ds);
        u4[(size_t)(node_a + 96) * 8 + cg] = r;
    }
}

// ================= gather aggregation =================

__global__ __launch_bounds__(256) void k_gather32(const float4* __restrict__ u4,
                                                  const int* __restrict__ es,
                                                  const int* __restrict__ offsets,
                                                  const float* __restrict__ dis,
                                                  const float* __restrict__ b,
                                                  float4* __restrict__ h4, int n) {
    int t = blockIdx.x * 256 + threadIdx.x;
    int node = t >> 3, q = t & 7;
    if (node >= n) return;
    int s0 = offsets[node];
    int s1 = offsets[node + 1];
    float4 acc = u4[(size_t)node * 8 + q];   // self-loop
    int ei = s0;
    for (; ei + 4 <= s1; ei += 4) {
        int e0 = es[ei], e1 = es[ei + 1], e2 = es[ei + 2], e3 = es[ei + 3];
        float4 v0 = u4[(size_t)e0 * 8 + q];
        float4 v1 = u4[(size_t)e1 * 8 + q];
        float4 v2 = u4[(size_t)e2 * 8 + q];
        float4 v3 = u4[(size_t)e3 * 8 + q];
        acc.x += (v0.x + v1.x) + (v2.x + v3.x);
        acc.y += (v0.y + v1.y) + (v2.y + v3.y);
        acc.z += (v0.z + v1.z) + (v2.z + v3.z);
        acc.w += (v0.w + v1.w) + (v2.w + v3.w);
    }
    for (; ei < s1; ++ei) {
        int s = es[ei];
        float4 v = u4[(size_t)s * 8 + q];
        acc.x += v.x; acc.y += v.y; acc.z += v.z; acc.w += v.w;
    }
    float ds = dis[node];
    float4 r;
    r.x = fmaxf(fmaf(ds, acc.x, b[q * 4 + 0]), 0.0f);
    r.y = fmaxf(fmaf(ds, acc.y, b[q * 4 + 1]), 0.0f);
    r.z = fmaxf(fmaf(ds, acc.z, b[q * 4 + 2]), 0.0f);
    r.w = fmaxf(fmaf(ds, acc.w, b[q * 4 + 3]), 0.0f);
    h4[(size_t)node * 8 + q] = r;
}

__global__ __launch_bounds__(256) void k_gather32_dot(const float4* __restrict__ u4,
                                                      const int* __restrict__ es,
                                                      const int* __restrict__ offsets,
                                                      const float* __restrict__ dis,
                                                      const float* __restrict__ b,
                                                      const float* __restrict__ W3,
                                                      float* __restrict__ s, int n) {
    int t = blockIdx.x * 256 + threadIdx.x;
    int node = t >> 3, q = t & 7;
    if (node >= n) return;
    int s0 = offsets[node];
    int s1 = offsets[node + 1];
    float4 acc = u4[(size_t)node * 8 + q];
    int ei = s0;
    for (; ei + 4 <= s1; ei += 4) {
        int e0 = es[ei], e1 = es[ei + 1], e2 = es[ei + 2], e3 = es[ei + 3];
        float4 v0 = u4[(size_t)e0 * 8 + q];
        float4 v1 = u4[(size_t)e1 * 8 + q];
        float4 v2 = u4[(size_t)e2 * 8 + q];
        float4 v3 = u4[(size_t)e3 * 8 + q];
        acc.x += (v0.x + v1.x) + (v2.x + v3.x);
        acc.y += (v0.y + v1.y) + (v2.y + v3.y);
        acc.z += (v0.z + v1.z) + (v2.z + v3.z);
        acc.w += (v0.w + v1.w) + (v2.w + v3.w);
    }
    for (; ei < s1; ++ei) {
        int sc = es[ei];
        float4 v = u4[(size_t)sc * 8 + q];
        acc.x += v.x; acc.y += v.y; acc.z += v.z; acc.w += v.w;
    }
    float ds = dis[node];
    float4 r;
    r.x = fmaxf(fmaf(ds, acc.x, b[q * 4 + 0]), 0.0f);
    r.y = fmaxf(fmaf(ds, acc.y, b[q * 4 + 1]), 0.0f);
    r.z = fmaxf(fmaf(ds, acc.z, b[q * 4 + 2]), 0.0f);
    r.w = fmaxf(fmaf(ds, acc.w, b[q * 4 + 3]), 0.0f);
    float p = r.x * W3[q * 4 + 0] + r.y * W3[q * 4 + 1]
            + r.z * W3[q * 4 + 2] + r.w * W3[q * 4 + 3];
    p += __shfl_down(p, 4, 8);
    p += __shfl_down(p, 2, 8);
    p += __shfl_down(p, 1, 8);
    if (q == 0) s[node] = p * ds;
}

__global__ void k_gather1(const float* __restrict__ sv, const int* __restrict__ es,
                          const int* __restrict__ offsets, const float* __restrict__ dis,
                          const float* __restrict__ b3, float* __restrict__ out, int n) {
    int d = blockIdx.x * 256 + threadIdx.x;
    if (d >= n) return;
    float acc = sv[d];
    int s0 = offsets[d], s1 = offsets[d + 1];
    int ei = s0;
    for (; ei + 4 <= s1; ei += 4) {
        float v0 = sv[es[ei]], v1 = sv[es[ei + 1]];
        float v2 = sv[es[ei + 2]], v3 = sv[es[ei + 3]];
        acc += (v0 + v1) + (v2 + v3);
    }
    for (; ei < s1; ++ei) acc += sv[es[ei]];
    float z = dis[d] * acc + b3[0];
    out[d] = 1.0f / (1.0f + expf(-z));
}

// ================= launch =================

extern "C" void kernel_launch(void* const* d_in, const int* in_sizes, int n_in,
                              void* d_out, int out_size, void* d_ws, size_t ws_size,
                              hipStream_t stream) {
    const float* x  = (const float*)d_in[0];
    const int*   ei = (const int*)d_in[1];
    const float* W1 = (const float*)d_in[2];
    const float* b1 = (const float*)d_in[3];
    const float* W2 = (const float*)d_in[4];
    const float* b2 = (const float*)d_in[5];
    const float* W3 = (const float*)d_in[6];
    const float* b3 = (const float*)d_in[7];
    float* out = (float*)d_out;

    int n = out_size;             // 150000
    int e = in_sizes[1] / 2;      // 2400000
    const int* src = ei;
    const int* dst = ei + e;

    int nbuckets = (n + NPB - 1) / NPB;   // 586

    float* A        = (float*)d_ws;                 // n*32 f
    float* B        = A + (size_t)n * HID;          // n*32 f (aliases tmp during CSR build)
    float* dis      = B + (size_t)n * HID;          // n f
    float* Cs       = dis + n;                      // n f
    int*   offsets  = (int*)(Cs + n);               // n+1 i
    int*   es       = offsets + (n + 1);            // e i
    int*   bin_hist = es + e;                       // nbuckets i
    int*   bin_off  = bin_hist + nbuckets;          // nbuckets+1 i
    int*   bin_cur  = bin_off + (nbuckets + 1);     // nbuckets i
    unsigned* tmp   = (unsigned*)B;

    dim3 blk(256);
    int gN    = (n + 255) / 256;
    int gN8   = (n * 8 + 255) / 256;
    int g128  = (n + 127) / 128;
    int gEb   = (e + EPB - 1) / EPB;   // 293

    // ---- CSR build ----
    hipMemsetAsync(bin_hist, 0, (size_t)nbuckets * sizeof(int), stream);
    k_bhist<<<gEb, dim3(BLK_E), 0, stream>>>(dst, bin_hist, e, nbuckets);
    k_bscan<<<1, 1024, 0, stream>>>(bin_hist, bin_off, bin_cur, offsets, nbuckets, n, e);
    k_bpart<<<gEb, dim3(BLK_E), 0, stream>>>(src, dst, bin_cur, tmp, e, nbuckets);
    k_bcsr <<<nbuckets, dim3(BLK_C), 0, stream>>>(tmp, bin_off, es, offsets, dis, n);

    // ---- layer 1 ----
    k_gemm1   <<<g128, blk, 0, stream>>>(x, W1, dis, A, n);
    k_gather32<<<gN8,  blk, 0, stream>>>((const float4*)A, es, offsets, dis, b1, (float4*)B, n);

    // ---- layer 2 (+ fused layer-3 transform) ----
    k_gemm2       <<<g128, blk, 0, stream>>>(B, W2, dis, A, n);
    k_gather32_dot<<<gN8,  blk, 0, stream>>>((const float4*)A, es, offsets, dis, b2, W3, Cs, n);

    // ---- layer 3 aggregation ----
    k_gather1<<<gN, blk, 0, stream>>>(Cs, es, offsets, dis, b3, out, n);
}

// Round 10
// 344.783 us; speedup vs baseline: 3.8116x; 2.2958x over previous
//
#include <hip/hip_runtime.h>
#include <math.h>

#define F_IN 128
#define HID  32

#define NPB   256      // nodes per bucket (dst >> 8)
#define MAXNB 1024     // max buckets supported by the one-block scan
#define EPB   8192     // edges per block in coarse passes (293 blocks @ 2.4M)
#define BLK_E 1024     // threads per block for coarse passes
#define BLK_C 512      // threads per block for k_bcsr

__device__ __forceinline__ void fma4(float4& a, float s, const float4& w) {
    a.x = fmaf(s, w.x, a.x);
    a.y = fmaf(s, w.y, a.y);
    a.z = fmaf(s, w.z, a.z);
    a.w = fmaf(s, w.w, a.w);
}

// ================= binned CSR build =================

__global__ __launch_bounds__(BLK_E) void k_bhist(const int* __restrict__ dst,
                                                 int* __restrict__ bin_hist,
                                                 int e, int nbuckets) {
    __shared__ int h[MAXNB];
    int tid = threadIdx.x;
    for (int i = tid; i < nbuckets; i += BLK_E) h[i] = 0;
    __syncthreads();
    int base = blockIdx.x * EPB;
    int end = base + EPB; if (end > e) end = e;
    for (int i = base + tid; i < end; i += BLK_E)
        atomicAdd(&h[dst[i] >> 8], 1);
    __syncthreads();
    for (int i = tid; i < nbuckets; i += BLK_E)
        if (h[i]) atomicAdd(&bin_hist[i], h[i]);
}

__global__ __launch_bounds__(1024) void k_bscan(const int* __restrict__ bin_hist,
                                                int* __restrict__ bin_off,
                                                int* __restrict__ bin_cur,
                                                int* __restrict__ offsets,
                                                int nbuckets, int n, int e) {
    __shared__ int sh[MAXNB];
    int t = threadIdx.x;
    int v = (t < nbuckets) ? bin_hist[t] : 0;
    sh[t] = v; __syncthreads();
    for (int off = 1; off < MAXNB; off <<= 1) {
        int a = (t >= off) ? sh[t - off] : 0;
        __syncthreads();
        sh[t] += a;
        __syncthreads();
    }
    int excl = sh[t] - v;
    if (t < nbuckets) { bin_off[t] = excl; bin_cur[t] = excl; }
    if (t == 0) { bin_off[nbuckets] = e; offsets[n] = e; }
}

__global__ __launch_bounds__(BLK_E) void k_bpart(const int* __restrict__ src,
                                                 const int* __restrict__ dst,
                                                 int* __restrict__ bin_cur,
                                                 unsigned* __restrict__ tmp,
                                                 int e, int nbuckets) {
    __shared__ int h[MAXNB];
    __shared__ int lc[MAXNB];
    int tid = threadIdx.x;
    for (int i = tid; i < nbuckets; i += BLK_E) h[i] = 0;
    __syncthreads();
    int base = blockIdx.x * EPB;
    int end = base + EPB; if (end > e) end = e;
    for (int i = base + tid; i < end; i += BLK_E)
        atomicAdd(&h[dst[i] >> 8], 1);
    __syncthreads();
    for (int i = tid; i < nbuckets; i += BLK_E) {
        int c = h[i];
        h[i] = c ? atomicAdd(&bin_cur[i], c) : 0;
        lc[i] = 0;
    }
    __syncthreads();
    for (int i = base + tid; i < end; i += BLK_E) {
        int d = dst[i];
        int b = d >> 8;
        int r = atomicAdd(&lc[b], 1);
        tmp[h[b] + r] = (unsigned)src[i] | ((unsigned)(d & (NPB - 1)) << 18);
    }
}

__global__ __launch_bounds__(BLK_C) void k_bcsr(const unsigned* __restrict__ tmp,
                                                const int* __restrict__ bin_off,
                                                int* __restrict__ es,
                                                int* __restrict__ offsets,
                                                float* __restrict__ dis, int n) {
    __shared__ int cnt[NPB];
    __shared__ int sh[NPB];
    __shared__ int cur[NPB];
    int b = blockIdx.x, t = threadIdx.x;
    if (t < NPB) cnt[t] = 0;
    __syncthreads();
    int s0 = bin_off[b], s1 = bin_off[b + 1];
    for (int i = s0 + t; i < s1; i += BLK_C)
        atomicAdd(&cnt[(tmp[i] >> 18) & (NPB - 1)], 1);
    __syncthreads();
    int v = (t < NPB) ? cnt[t] : 0;
    if (t < NPB) sh[t] = v;
    __syncthreads();
    for (int off = 1; off < NPB; off <<= 1) {
        int a = (t < NPB && t >= off) ? sh[t - off] : 0;
        __syncthreads();
        if (t < NPB) sh[t] += a;
        __syncthreads();
    }
    if (t < NPB) {
        int excl = sh[t] - v;
        int node = b * NPB + t;
        if (node < n) {
            offsets[node] = s0 + excl;
            dis[node] = rsqrtf((float)(v + 1));
        }
        cur[t] = excl;
    }
    __syncthreads();
    for (int i = s0 + t; i < s1; i += BLK_C) {
        unsigned w = tmp[i];
        int dl = (w >> 18) & (NPB - 1);
        int r = atomicAdd(&cur[dl], 1);
        es[s0 + r] = (int)(w & 0x3FFFFu);
    }
}

// ================= transforms =================

// R7-proven loop shape (in-iteration xv[] array, partial unroll, no
// launch-bounds VGPR squeeze), decomposition changed to 64 nodes/block
// (m=2) so the grid fills ~32 waves/CU for latency hiding.
__global__ __launch_bounds__(256) void k_gemm1(const float* __restrict__ x,
                                               const float* __restrict__ W,
                                               const float* __restrict__ dis,
                                               float* __restrict__ u, int n) {
    __shared__ float Ws[F_IN * HID];
    int tid = threadIdx.x;
    for (int i = tid; i < F_IN * HID; i += 256) Ws[i] = W[i];
    int node0 = blockIdx.x * 64;
    int cg = tid & 7, gq = tid >> 3;
    int row[2];
#pragma unroll
    for (int m = 0; m < 2; ++m) {
        int node = node0 + gq + 32 * m;
        row[m] = (node < n) ? node : 0;
    }
    const float4* x4 = (const float4*)x;
    float4 acc[2];
#pragma unroll
    for (int m = 0; m < 2; ++m) acc[m] = make_float4(0.f, 0.f, 0.f, 0.f);
    __syncthreads();
#pragma unroll 4
    for (int ks = 0; ks < 32; ++ks) {
        float4 xv[2];
#pragma unroll
        for (int m = 0; m < 2; ++m) xv[m] = x4[(size_t)row[m] * 32 + ks];
        float4 w0 = *(const float4*)&Ws[(ks * 4 + 0) * HID + cg * 4];
        float4 w1 = *(const float4*)&Ws[(ks * 4 + 1) * HID + cg * 4];
        float4 w2 = *(const float4*)&Ws[(ks * 4 + 2) * HID + cg * 4];
        float4 w3 = *(const float4*)&Ws[(ks * 4 + 3) * HID + cg * 4];
#pragma unroll
        for (int m = 0; m < 2; ++m) {
            fma4(acc[m], xv[m].x, w0);
            fma4(acc[m], xv[m].y, w1);
            fma4(acc[m], xv[m].z, w2);
            fma4(acc[m], xv[m].w, w3);
        }
    }
#pragma unroll
    for (int m = 0; m < 2; ++m) {
        int node = node0 + gq + 32 * m;
        if (node < n) {
            float ds = dis[node];
            float4 r;
            r.x = acc[m].x * ds; r.y = acc[m].y * ds;
            r.z = acc[m].z * ds; r.w = acc[m].w * ds;
            *(float4*)&u[(size_t)node * HID + cg * 4] = r;
        }
    }
}

__global__ __launch_bounds__(256) void k_gemm2(const float* __restrict__ h,
                                               const float* __restrict__ W,
                                               const float* __restrict__ dis,
                                               float* __restrict__ u, int n) {
    __shared__ float Ws[HID * HID];
    int tid = threadIdx.x;
    for (int i = tid; i < HID * HID; i += 256) Ws[i] = W[i];
    int node0 = blockIdx.x * 64;
    int cg = tid & 7, gq = tid >> 3;
    int row[2];
#pragma unroll
    for (int m = 0; m < 2; ++m) {
        int node = node0 + gq + 32 * m;
        row[m] = (node < n) ? node : 0;
    }
    const float4* h4 = (const float4*)h;
    float4 acc[2];
#pragma unroll
    for (int m = 0; m < 2; ++m) acc[m] = make_float4(0.f, 0.f, 0.f, 0.f);
    __syncthreads();
#pragma unroll 4
    for (int ks = 0; ks < 8; ++ks) {
        float4 xv[2];
#pragma unroll
        for (int m = 0; m < 2; ++m) xv[m] = h4[(size_t)row[m] * 8 + ks];
        float4 w0 = *(const float4*)&Ws[(ks * 4 + 0) * HID + cg * 4];
        float4 w1 = *(const float4*)&Ws[(ks * 4 + 1) * HID + cg * 4];
        float4 w2 = *(const float4*)&Ws[(ks * 4 + 2) * HID + cg * 4];
        float4 w3 = *(const float4*)&Ws[(ks * 4 + 3) * HID + cg * 4];
#pragma unroll
        for (int m = 0; m < 2; ++m) {
            fma4(acc[m], xv[m].x, w0);
            fma4(acc[m], xv[m].y, w1);
            fma4(acc[m], xv[m].z, w2);
            fma4(acc[m], xv[m].w, w3);
        }
    }
#pragma unroll
    for (int m = 0; m < 2; ++m) {
        int node = node0 + gq + 32 * m;
        if (node < n) {
            float ds = dis[node];
            float4 r;
            r.x = acc[m].x * ds; r.y = acc[m].y * ds;
            r.z = acc[m].z * ds; r.w = acc[m].w * ds;
            *(float4*)&u[(size_t)node * HID + cg * 4] = r;
        }
    }
}

// ================= gather aggregation =================

__global__ __launch_bounds__(256) void k_gather32(const float4* __restrict__ u4,
                                                  const int* __restrict__ es,
                                                  const int* __restrict__ offsets,
                                                  const float* __restrict__ dis,
                                                  const float* __restrict__ b,
                                                  float4* __restrict__ h4, int n) {
    int t = blockIdx.x * 256 + threadIdx.x;
    int node = t >> 3, q = t & 7;
    if (node >= n) return;
    int s0 = offsets[node];
    int s1 = offsets[node + 1];
    float4 acc = u4[(size_t)node * 8 + q];   // self-loop
    int ei = s0;
    for (; ei + 4 <= s1; ei += 4) {
        int e0 = es[ei], e1 = es[ei + 1], e2 = es[ei + 2], e3 = es[ei + 3];
        float4 v0 = u4[(size_t)e0 * 8 + q];
        float4 v1 = u4[(size_t)e1 * 8 + q];
        float4 v2 = u4[(size_t)e2 * 8 + q];
        float4 v3 = u4[(size_t)e3 * 8 + q];
        acc.x += (v0.x + v1.x) + (v2.x + v3.x);
        acc.y += (v0.y + v1.y) + (v2.y + v3.y);
        acc.z += (v0.z + v1.z) + (v2.z + v3.z);
        acc.w += (v0.w + v1.w) + (v2.w + v3.w);
    }
    for (; ei < s1; ++ei) {
        int s = es[ei];
        float4 v = u4[(size_t)s * 8 + q];
        acc.x += v.x; acc.y += v.y; acc.z += v.z; acc.w += v.w;
    }
    float ds = dis[node];
    float4 r;
    r.x = fmaxf(fmaf(ds, acc.x, b[q * 4 + 0]), 0.0f);
    r.y = fmaxf(fmaf(ds, acc.y, b[q * 4 + 1]), 0.0f);
    r.z = fmaxf(fmaf(ds, acc.z, b[q * 4 + 2]), 0.0f);
    r.w = fmaxf(fmaf(ds, acc.w, b[q * 4 + 3]), 0.0f);
    h4[(size_t)node * 8 + q] = r;
}

__global__ __launch_bounds__(256) void k_gather32_dot(const float4* __restrict__ u4,
                                                      const int* __restrict__ es,
                                                      const int* __restrict__ offsets,
                                                      const float* __restrict__ dis,
                                                      const float* __restrict__ b,
                                                      const float* __restrict__ W3,
                                                      float* __restrict__ s, int n) {
    int t = blockIdx.x * 256 + threadIdx.x;
    int node = t >> 3, q = t & 7;
    if (node >= n) return;
    int s0 = offsets[node];
    int s1 = offsets[node + 1];
    float4 acc = u4[(size_t)node * 8 + q];
    int ei = s0;
    for (; ei + 4 <= s1; ei += 4) {
        int e0 = es[ei], e1 = es[ei + 1], e2 = es[ei + 2], e3 = es[ei + 3];
        float4 v0 = u4[(size_t)e0 * 8 + q];
        float4 v1 = u4[(size_t)e1 * 8 + q];
        float4 v2 = u4[(size_t)e2 * 8 + q];
        float4 v3 = u4[(size_t)e3 * 8 + q];
        acc.x += (v0.x + v1.x) + (v2.x + v3.x);
        acc.y += (v0.y + v1.y) + (v2.y + v3.y);
        acc.z += (v0.z + v1.z) + (v2.z + v3.z);
        acc.w += (v0.w + v1.w) + (v2.w + v3.w);
    }
    for (; ei < s1; ++ei) {
        int sc = es[ei];
        float4 v = u4[(size_t)sc * 8 + q];
        acc.x += v.x; acc.y += v.y; acc.z += v.z; acc.w += v.w;
    }
    float ds = dis[node];
    float4 r;
    r.x = fmaxf(fmaf(ds, acc.x, b[q * 4 + 0]), 0.0f);
    r.y = fmaxf(fmaf(ds, acc.y, b[q * 4 + 1]), 0.0f);
    r.z = fmaxf(fmaf(ds, acc.z, b[q * 4 + 2]), 0.0f);
    r.w = fmaxf(fmaf(ds, acc.w, b[q * 4 + 3]), 0.0f);
    float p = r.x * W3[q * 4 + 0] + r.y * W3[q * 4 + 1]
            + r.z * W3[q * 4 + 2] + r.w * W3[q * 4 + 3];
    p += __shfl_down(p, 4, 8);
    p += __shfl_down(p, 2, 8);
    p += __shfl_down(p, 1, 8);
    if (q == 0) s[node] = p * ds;
}

__global__ void k_gather1(const float* __restrict__ sv, const int* __restrict__ es,
                          const int* __restrict__ offsets, const float* __restrict__ dis,
                          const float* __restrict__ b3, float* __restrict__ out, int n) {
    int d = blockIdx.x * 256 + threadIdx.x;
    if (d >= n) return;
    float acc = sv[d];
    int s0 = offsets[d], s1 = offsets[d + 1];
    int ei = s0;
    for (; ei + 4 <= s1; ei += 4) {
        float v0 = sv[es[ei]], v1 = sv[es[ei + 1]];
        float v2 = sv[es[ei + 2]], v3 = sv[es[ei + 3]];
        acc += (v0 + v1) + (v2 + v3);
    }
    for (; ei < s1; ++ei) acc += sv[es[ei]];
    float z = dis[d] * acc + b3[0];
    out[d] = 1.0f / (1.0f + expf(-z));
}

// ================= launch =================

extern "C" void kernel_launch(void* const* d_in, const int* in_sizes, int n_in,
                              void* d_out, int out_size, void* d_ws, size_t ws_size,
                              hipStream_t stream) {
    const float* x  = (const float*)d_in[0];
    const int*   ei = (const int*)d_in[1];
    const float* W1 = (const float*)d_in[2];
    const float* b1 = (const float*)d_in[3];
    const float* W2 = (const float*)d_in[4];
    const float* b2 = (const float*)d_in[5];
    const float* W3 = (const float*)d_in[6];
    const float* b3 = (const float*)d_in[7];
    float* out = (float*)d_out;

    int n = out_size;             // 150000
    int e = in_sizes[1] / 2;      // 2400000
    const int* src = ei;
    const int* dst = ei + e;

    int nbuckets = (n + NPB - 1) / NPB;   // 586

    float* A        = (float*)d_ws;                 // n*32 f
    float* B        = A + (size_t)n * HID;          // n*32 f (aliases tmp during CSR build)
    float* dis      = B + (size_t)n * HID;          // n f
    float* Cs       = dis + n;                      // n f
    int*   offsets  = (int*)(Cs + n);               // n+1 i
    int*   es       = offsets + (n + 1);            // e i
    int*   bin_hist = es + e;                       // nbuckets i
    int*   bin_off  = bin_hist + nbuckets;          // nbuckets+1 i
    int*   bin_cur  = bin_off + (nbuckets + 1);     // nbuckets i
    unsigned* tmp   = (unsigned*)B;

    dim3 blk(256);
    int gN    = (n + 255) / 256;
    int gN8   = (n * 8 + 255) / 256;
    int g64   = (n + 63) / 64;         // 2344
    int gEb   = (e + EPB - 1) / EPB;   // 293

    // ---- CSR build ----
    hipMemsetAsync(bin_hist, 0, (size_t)nbuckets * sizeof(int), stream);
    k_bhist<<<gEb, dim3(BLK_E), 0, stream>>>(dst, bin_hist, e, nbuckets);
    k_bscan<<<1, 1024, 0, stream>>>(bin_hist, bin_off, bin_cur, offsets, nbuckets, n, e);
    k_bpart<<<gEb, dim3(BLK_E), 0, stream>>>(src, dst, bin_cur, tmp, e, nbuckets);
    k_bcsr <<<nbuckets, dim3(BLK_C), 0, stream>>>(tmp, bin_off, es, offsets, dis, n);

    // ---- layer 1 ----
    k_gemm1   <<<g64, blk, 0, stream>>>(x, W1, dis, A, n);
    k_gather32<<<gN8, blk, 0, stream>>>((const float4*)A, es, offsets, dis, b1, (float4*)B, n);

    // ---- layer 2 (+ fused layer-3 transform) ----
    k_gemm2       <<<g64, blk, 0, stream>>>(B, W2, dis, A, n);
    k_gather32_dot<<<gN8, blk, 0, stream>>>((const float4*)A, es, offsets, dis, b2, W3, Cs, n);

    // ---- layer 3 aggregation ----
    k_gather1<<<gN, blk, 0, stream>>>(Cs, es, offsets, dis, b3, out, n);
}